// Round 1
// baseline (517.682 us; speedup 1.0000x reference)
//
#include <hip/hip_runtime.h>
#include <math.h>

#define B_TOTAL 131072
#define D 128
#define K 64
#define NNEG 5
#define PAD 132            // 132%8==4 -> lanes 0..7 of a b128 row-read cover all 32 banks; 16B-aligned rows
#define BLOCK 256
#define GRID 1024
#define WAVES_PER_BLOCK 4
#define TOTAL_WAVES (GRID * WAVES_PER_BLOCK)   // 4096; B_TOTAL/4096 = 32 iterations per wave (exact)

__device__ __forceinline__ float wave_sum(float v) {
#pragma unroll
    for (int m = 1; m < 64; m <<= 1) v += __shfl_xor(v, m, 64);
    return v;  // broadcast: all lanes hold the sum
}

__device__ __forceinline__ float wave_max(float v) {
#pragma unroll
    for (int m = 1; m < 64; m <<= 1) v = fmaxf(v, __shfl_xor(v, m, 64));
    return v;
}

// log_sigmoid(x) = min(x,0) - log1p(exp(-|x|))
__device__ __forceinline__ float log_sigmoid(float x) {
    return fminf(x, 0.f) - log1pf(__expf(-fabsf(x)));
}

__global__ void zero_loss(float* out) {
    if (threadIdx.x == 0 && blockIdx.x == 0) out[0] = 0.f;
}

__global__ __launch_bounds__(BLOCK, 4) void gcn_gumbel_kernel(
        const int* __restrict__ w, const int* __restrict__ c,
        const int* __restrict__ neg,
        const float* __restrict__ node_emb, const float* __restrict__ ctx_emb,
        const float* __restrict__ comm_w, float* __restrict__ out) {
    __shared__ float cw[K * PAD];                       // 33792 B
    __shared__ float a_s[WAVES_PER_BLOCK][D];           // we*ce broadcast
    __shared__ float we_s[WAVES_PER_BLOCK][D];
    __shared__ float q_s[WAVES_PER_BLOCK][K];

    const int tid = threadIdx.x;
    const int lane = tid & 63;
    const int wid = tid >> 6;

    // stage comm_w (row-major [K][D]) into padded LDS, coalesced float4
    for (int i = tid * 4; i < K * D; i += BLOCK * 4) {
        float4 v = *(const float4*)(comm_w + i);
        int row = i >> 7, col = i & 127;
        *(float4*)&cw[row * PAD + col] = v;
    }

    float* __restrict__ outq = out + 1;
    float* __restrict__ outp = out + 1 + (size_t)B_TOTAL * K;

    float wave_loss = 0.f;
    const int gw = blockIdx.x * WAVES_PER_BLOCK + wid;

    for (int b = gw; b < B_TOTAL; b += TOTAL_WAVES) {
        const int iw = w[b], ic = c[b];
        const float2 we2 = *(const float2*)(node_emb + (size_t)iw * D + 2 * lane);
        const float2 ce2 = *(const float2*)(node_emb + (size_t)ic * D + 2 * lane);
        const float2 cc2 = *(const float2*)(ctx_emb + (size_t)ic * D + 2 * lane);
        *(float2*)&a_s[wid][2 * lane] = make_float2(we2.x * ce2.x, we2.y * ce2.y);
        *(float2*)&we_s[wid][2 * lane] = we2;
        __syncthreads();  // a/we visible (also orders vs prev iter's q_s reads)

        // q[k] = (we*ce) . cw[k]   and  prior-logit[k] = we . cw[k], k = lane
        float q = 0.f, pl = 0.f;
        const float* cwrow = &cw[lane * PAD];
#pragma unroll 8
        for (int j = 0; j < D; j += 4) {
            float4 c4 = *(const float4*)(cwrow + j);
            float4 a4 = *(const float4*)&a_s[wid][j];
            float4 w4 = *(const float4*)&we_s[wid][j];
            q  += a4.x * c4.x + a4.y * c4.y + a4.z * c4.z + a4.w * c4.w;
            pl += w4.x * c4.x + w4.y * c4.y + w4.z * c4.z + w4.w * c4.w;
        }
        q_s[wid][lane] = q;
        __syncthreads();  // q visible (also orders vs next iter's a_s writes)

        // r[d] = sum_k q[k]*cw[k][d], this lane owns d = 2*lane, 2*lane+1
        float r0 = 0.f, r1 = 0.f;
#pragma unroll 8
        for (int k = 0; k < K; ++k) {
            float qk = q_s[wid][k];
            float2 cwk = *(const float2*)&cw[k * PAD + 2 * lane];
            r0 += qk * cwk.x;
            r1 += qk * cwk.y;
        }

        // softmax(q) over K (lane=k)
        float mq = wave_max(q);
        float eq = __expf(q - mq);
        float sq = wave_sum(eq);
        outq[(size_t)b * K + lane] = eq / sq;

        // prior = softmax(we @ cw^T)
        float mp = wave_max(pl);
        float ep = __expf(pl - mp);
        float sp = wave_sum(ep);
        outp[(size_t)b * K + lane] = ep / sp;

        // pos = c_ctx . r
        float pos = wave_sum(cc2.x * r0 + cc2.y * r1);
        float contrib = log_sigmoid(pos);

#pragma unroll
        for (int n = 0; n < NNEG; ++n) {
            int jn = neg[b * NNEG + n];
            float2 ne = *(const float2*)(ctx_emb + (size_t)jn * D + 2 * lane);
            float np = wave_sum(ne.x * r0 + ne.y * r1);
            contrib += log_sigmoid(-np);
        }
        wave_loss += contrib;
    }

    if (lane == 0) atomicAdd(out, -wave_loss / (float)B_TOTAL);
}

extern "C" void kernel_launch(void* const* d_in, const int* in_sizes, int n_in,
                              void* d_out, int out_size, void* d_ws, size_t ws_size,
                              hipStream_t stream) {
    const int* w = (const int*)d_in[0];
    const int* c = (const int*)d_in[1];
    const int* neg = (const int*)d_in[2];
    // d_in[3] = temp (unused scalar)
    const float* node_emb = (const float*)d_in[4];
    const float* ctx_emb = (const float*)d_in[5];
    const float* comm_w = (const float*)d_in[6];
    float* out = (float*)d_out;

    zero_loss<<<1, 64, 0, stream>>>(out);
    gcn_gumbel_kernel<<<GRID, BLOCK, 0, stream>>>(w, c, neg, node_emb, ctx_emb, comm_w, out);
}

// Round 2
// 294.242 us; speedup vs baseline: 1.7594x; 1.7594x over previous
//
#include <hip/hip_runtime.h>
#include <math.h>

#define B_TOTAL 131072
#define D 128
#define K 64
#define NNEG 5
#define TILE 16
#define BLOCK 256
#define WPB 4
#define NTILES (B_TOTAL / TILE)        // 8192
#define GRID (NTILES / WPB)            // 2048
#define CWS 136                        // bf16 row stride: 272B, 16B-aligned

typedef __attribute__((ext_vector_type(8))) short bf16x8;
typedef __attribute__((ext_vector_type(4))) float f32x4;

union FragU { unsigned u[4]; bf16x8 v; };

// pack two fp32 -> bf16x2 (truncation; error budget is huge: threshold 0.62)
__device__ __forceinline__ unsigned pkbf(float lo, float hi) {
    return __builtin_amdgcn_perm(__float_as_uint(hi), __float_as_uint(lo), 0x07060302u);
}

__device__ __forceinline__ float log_sigmoid(float x) {
    return fminf(x, 0.f) - __logf(1.f + __expf(-fabsf(x)));
}

__global__ void zero_loss(float* out) { if (threadIdx.x == 0) out[0] = 0.f; }

__global__ __launch_bounds__(BLOCK) void gcn_mfma_kernel(
    const int* __restrict__ w, const int* __restrict__ c, const int* __restrict__ neg,
    const float* __restrict__ node_emb, const float* __restrict__ ctx_emb,
    const float* __restrict__ comm_w, float* __restrict__ out)
{
    __shared__ __align__(16) short cw_lds[K * CWS];
    const int tid = threadIdx.x;
    const int lane = tid & 63;
    const int wid = tid >> 6;
    const int i15 = lane & 15;
    const int g = lane >> 4;

    // stage comm_w fp32 -> bf16 LDS rows [K][D] (stride CWS)
    for (int i = tid * 4; i < K * D; i += BLOCK * 4) {
        float4 v = *(const float4*)(comm_w + i);
        int row = i >> 7, col = i & 127;
        unsigned* dst = (unsigned*)&cw_lds[row * CWS + col];
        dst[0] = pkbf(v.x, v.y);
        dst[1] = pkbf(v.z, v.w);
    }
    __syncthreads();

    // B fragments (shared by ALL eight GEMMs): lane holds cw[n=lane&15+16*nb][k0+(lane>>4)*8 + 0..7]
    bf16x8 bfr[4][4];
#pragma unroll
    for (int ks = 0; ks < 4; ++ks)
#pragma unroll
        for (int nb = 0; nb < 4; ++nb)
            bfr[ks][nb] = *(const bf16x8*)&cw_lds[(nb * 16 + i15) * CWS + ks * 32 + g * 8];

    const int tile = blockIdx.x * WPB + wid;   // 8192 tiles of 16 pairs, exact
    const int b0 = tile * TILE;
    const int bm = b0 + i15;
    const int iw = w[bm], ic = c[bm];
    int ing[NNEG];
#pragma unroll
    for (int j = 0; j < NNEG; ++j) ing[j] = neg[bm * NNEG + j];

    const f32x4 z4 = {0.f, 0.f, 0.f, 0.f};
    f32x4 Qa[4] = {z4, z4, z4, z4};   // q = (we*ce) @ cw^T
    f32x4 Pa[4] = {z4, z4, z4, z4};   // prior logits = we @ cw^T

#pragma unroll
    for (int ks = 0; ks < 4; ++ks) {
        const float* wp = node_emb + (size_t)iw * D + ks * 32 + g * 8;
        const float* cp = node_emb + (size_t)ic * D + ks * 32 + g * 8;
        float4 w0 = *(const float4*)wp, w1 = *(const float4*)(wp + 4);
        float4 c0 = *(const float4*)cp, c1 = *(const float4*)(cp + 4);
        FragU wf, pf;
        wf.u[0] = pkbf(w0.x, w0.y);             wf.u[1] = pkbf(w0.z, w0.w);
        wf.u[2] = pkbf(w1.x, w1.y);             wf.u[3] = pkbf(w1.z, w1.w);
        pf.u[0] = pkbf(w0.x * c0.x, w0.y * c0.y); pf.u[1] = pkbf(w0.z * c0.z, w0.w * c0.w);
        pf.u[2] = pkbf(w1.x * c1.x, w1.y * c1.y); pf.u[3] = pkbf(w1.z * c1.z, w1.w * c1.w);
#pragma unroll
        for (int nb = 0; nb < 4; ++nb) {
            Pa[nb] = __builtin_amdgcn_mfma_f32_16x16x32_bf16(wf.v, bfr[ks][nb], Pa[nb], 0, 0, 0);
            Qa[nb] = __builtin_amdgcn_mfma_f32_16x16x32_bf16(pf.v, bfr[ks][nb], Qa[nb], 0, 0, 0);
        }
    }

    // pos/neg: F_j = e_j @ cw^T in C-layout; dot rows of F_j with rows of Q (same layout)
    float lossAcc = 0.f;
#pragma unroll
    for (int j = 0; j < 1 + NNEG; ++j) {
        const int idx = (j == 0) ? ic : ing[j - 1];
        const float* ebase = ctx_emb + (size_t)idx * D;
        f32x4 Fa[4] = {z4, z4, z4, z4};
#pragma unroll
        for (int ks = 0; ks < 4; ++ks) {
            const float* ep = ebase + ks * 32 + g * 8;
            float4 e0 = *(const float4*)ep, e1 = *(const float4*)(ep + 4);
            FragU ef;
            ef.u[0] = pkbf(e0.x, e0.y); ef.u[1] = pkbf(e0.z, e0.w);
            ef.u[2] = pkbf(e1.x, e1.y); ef.u[3] = pkbf(e1.z, e1.w);
#pragma unroll
            for (int nb = 0; nb < 4; ++nb)
                Fa[nb] = __builtin_amdgcn_mfma_f32_16x16x32_bf16(ef.v, bfr[ks][nb], Fa[nb], 0, 0, 0);
        }
#pragma unroll
        for (int r = 0; r < 4; ++r) {
            // row (g*4+r): cols spread over lanes of this 16-lane group x 4 nb tiles
            float s = Fa[0][r] * Qa[0][r] + Fa[1][r] * Qa[1][r] + Fa[2][r] * Qa[2][r] + Fa[3][r] * Qa[3][r];
            s += __shfl_xor(s, 1, 64);
            s += __shfl_xor(s, 2, 64);
            s += __shfl_xor(s, 4, 64);
            s += __shfl_xor(s, 8, 64);
            lossAcc += log_sigmoid(j == 0 ? s : -s);   // replicated x16 lanes; scaled at the end
        }
    }

    // softmax(q) and prior = softmax(we@cw^T); C layout: row=(g*4+r), col=i15+16*nb
    float* __restrict__ outq = out + 1;
    float* __restrict__ outp = out + 1 + (size_t)B_TOTAL * K;
#pragma unroll
    for (int r = 0; r < 4; ++r) {
        const size_t obase = (size_t)(b0 + g * 4 + r) * K + i15;
        {
            float m = fmaxf(fmaxf(Qa[0][r], Qa[1][r]), fmaxf(Qa[2][r], Qa[3][r]));
            m = fmaxf(m, __shfl_xor(m, 1, 64)); m = fmaxf(m, __shfl_xor(m, 2, 64));
            m = fmaxf(m, __shfl_xor(m, 4, 64)); m = fmaxf(m, __shfl_xor(m, 8, 64));
            float e0 = __expf(Qa[0][r] - m), e1 = __expf(Qa[1][r] - m);
            float e2 = __expf(Qa[2][r] - m), e3 = __expf(Qa[3][r] - m);
            float s = e0 + e1 + e2 + e3;
            s += __shfl_xor(s, 1, 64); s += __shfl_xor(s, 2, 64);
            s += __shfl_xor(s, 4, 64); s += __shfl_xor(s, 8, 64);
            float inv = 1.f / s;
            outq[obase]      = e0 * inv; outq[obase + 16] = e1 * inv;
            outq[obase + 32] = e2 * inv; outq[obase + 48] = e3 * inv;
        }
        {
            float m = fmaxf(fmaxf(Pa[0][r], Pa[1][r]), fmaxf(Pa[2][r], Pa[3][r]));
            m = fmaxf(m, __shfl_xor(m, 1, 64)); m = fmaxf(m, __shfl_xor(m, 2, 64));
            m = fmaxf(m, __shfl_xor(m, 4, 64)); m = fmaxf(m, __shfl_xor(m, 8, 64));
            float e0 = __expf(Pa[0][r] - m), e1 = __expf(Pa[1][r] - m);
            float e2 = __expf(Pa[2][r] - m), e3 = __expf(Pa[3][r] - m);
            float s = e0 + e1 + e2 + e3;
            s += __shfl_xor(s, 1, 64); s += __shfl_xor(s, 2, 64);
            s += __shfl_xor(s, 4, 64); s += __shfl_xor(s, 8, 64);
            float inv = 1.f / s;
            outp[obase]      = e0 * inv; outp[obase + 16] = e1 * inv;
            outp[obase + 32] = e2 * inv; outp[obase + 48] = e3 * inv;
        }
    }

    float tot = lossAcc;
#pragma unroll
    for (int msk = 1; msk < 64; msk <<= 1) tot += __shfl_xor(tot, msk, 64);
    if (lane == 0) atomicAdd(out, -tot / (16.f * (float)B_TOTAL));  // /16: per-row x16 lane replication
}

extern "C" void kernel_launch(void* const* d_in, const int* in_sizes, int n_in,
                              void* d_out, int out_size, void* d_ws, size_t ws_size,
                              hipStream_t stream) {
    const int* w = (const int*)d_in[0];
    const int* c = (const int*)d_in[1];
    const int* neg = (const int*)d_in[2];
    // d_in[3] = temp (unused)
    const float* node_emb = (const float*)d_in[4];
    const float* ctx_emb = (const float*)d_in[5];
    const float* comm_w = (const float*)d_in[6];
    float* out = (float*)d_out;

    zero_loss<<<1, 64, 0, stream>>>(out);
    gcn_mfma_kernel<<<GRID, BLOCK, 0, stream>>>(w, c, neg, node_emb, ctx_emb, comm_w, out);
}

// Round 3
// 290.739 us; speedup vs baseline: 1.7806x; 1.0121x over previous
//
#include <hip/hip_runtime.h>
#include <math.h>

#define SIZE_N 100000
#define B_TOTAL 131072
#define D 128
#define K 64
#define NNEG 5
#define TILE 16
#define BLOCK 256
#define WPB 4
#define NTILES (B_TOTAL / TILE)        // 8192
#define GRID (NTILES / WPB)            // 2048
#define CWS 136                        // bf16 row stride: 272B, 16B-aligned

typedef __attribute__((ext_vector_type(8))) short bf16x8;
typedef __attribute__((ext_vector_type(4))) float f32x4;

union FragU { unsigned u[4]; bf16x8 v; };

// pack two fp32 -> bf16x2 (truncation; threshold 0.62 gives huge margin)
__device__ __forceinline__ unsigned pkbf(float lo, float hi) {
    return __builtin_amdgcn_perm(__float_as_uint(hi), __float_as_uint(lo), 0x07060302u);
}

__device__ __forceinline__ float log_sigmoid(float x) {
    return fminf(x, 0.f) - __logf(1.f + __expf(-fabsf(x)));
}

__global__ void zero_loss(float* out) { if (threadIdx.x == 0) out[0] = 0.f; }

// fp32 -> bf16 table conversion (both tables), fused loss-zero
__global__ __launch_bounds__(BLOCK) void convert_tables(
    const float* __restrict__ a, const float* __restrict__ b,
    short* __restrict__ oa, short* __restrict__ ob, float* __restrict__ out)
{
    if (blockIdx.x == 0 && threadIdx.x == 0) out[0] = 0.f;
    const size_t n = (size_t)SIZE_N * D;           // 12.8M elems
    size_t i = ((size_t)blockIdx.x * BLOCK + threadIdx.x) * 8;
    if (i >= n) return;
    {
        float4 v0 = *(const float4*)(a + i), v1 = *(const float4*)(a + i + 4);
        FragU f;
        f.u[0] = pkbf(v0.x, v0.y); f.u[1] = pkbf(v0.z, v0.w);
        f.u[2] = pkbf(v1.x, v1.y); f.u[3] = pkbf(v1.z, v1.w);
        *(bf16x8*)(oa + i) = f.v;
    }
    {
        float4 v0 = *(const float4*)(b + i), v1 = *(const float4*)(b + i + 4);
        FragU f;
        f.u[0] = pkbf(v0.x, v0.y); f.u[1] = pkbf(v0.z, v0.w);
        f.u[2] = pkbf(v1.x, v1.y); f.u[3] = pkbf(v1.z, v1.w);
        *(bf16x8*)(ob + i) = f.v;
    }
}

// ---------------- bf16-gather main kernel ----------------
__global__ __launch_bounds__(BLOCK) void gcn_mfma_bf16(
    const int* __restrict__ w, const int* __restrict__ c, const int* __restrict__ neg,
    const short* __restrict__ nodeb, const short* __restrict__ ctxb,
    const float* __restrict__ comm_w, float* __restrict__ out)
{
    __shared__ __align__(16) short cw_lds[K * CWS];
    const int tid = threadIdx.x;
    const int lane = tid & 63;
    const int wid = tid >> 6;
    const int i15 = lane & 15;
    const int g = lane >> 4;

    for (int i = tid * 4; i < K * D; i += BLOCK * 4) {
        float4 v = *(const float4*)(comm_w + i);
        int row = i >> 7, col = i & 127;
        unsigned* dst = (unsigned*)&cw_lds[row * CWS + col];
        dst[0] = pkbf(v.x, v.y);
        dst[1] = pkbf(v.z, v.w);
    }
    __syncthreads();

    bf16x8 bfr[4][4];
#pragma unroll
    for (int ks = 0; ks < 4; ++ks)
#pragma unroll
        for (int nb = 0; nb < 4; ++nb)
            bfr[ks][nb] = *(const bf16x8*)&cw_lds[(nb * 16 + i15) * CWS + ks * 32 + g * 8];

    const int tile = blockIdx.x * WPB + wid;
    const int b0 = tile * TILE;
    const int bm = b0 + i15;
    const int iw = w[bm], ic = c[bm];
    int ing[NNEG];
#pragma unroll
    for (int j = 0; j < NNEG; ++j) ing[j] = neg[bm * NNEG + j];

    const f32x4 z4 = {0.f, 0.f, 0.f, 0.f};
    f32x4 Qa[4] = {z4, z4, z4, z4};
    f32x4 Pa[4] = {z4, z4, z4, z4};

    const short* wp = nodeb + (size_t)iw * D + g * 8;
    const short* cp = nodeb + (size_t)ic * D + g * 8;
#pragma unroll
    for (int ks = 0; ks < 4; ++ks) {
        FragU wf, cf, pf;
        wf.v = *(const bf16x8*)(wp + ks * 32);
        cf.v = *(const bf16x8*)(cp + ks * 32);
#pragma unroll
        for (int t = 0; t < 4; ++t) {
            float al = __uint_as_float(wf.u[t] << 16);
            float ah = __uint_as_float(wf.u[t] & 0xffff0000u);
            float bl = __uint_as_float(cf.u[t] << 16);
            float bh = __uint_as_float(cf.u[t] & 0xffff0000u);
            pf.u[t] = pkbf(al * bl, ah * bh);
        }
#pragma unroll
        for (int nb = 0; nb < 4; ++nb) {
            Pa[nb] = __builtin_amdgcn_mfma_f32_16x16x32_bf16(wf.v, bfr[ks][nb], Pa[nb], 0, 0, 0);
            Qa[nb] = __builtin_amdgcn_mfma_f32_16x16x32_bf16(pf.v, bfr[ks][nb], Qa[nb], 0, 0, 0);
        }
    }

    float lossAcc = 0.f;
#pragma unroll
    for (int j = 0; j < 1 + NNEG; ++j) {
        const int idx = (j == 0) ? ic : ing[j - 1];
        const short* ep = ctxb + (size_t)idx * D + g * 8;
        bf16x8 ef[4];
#pragma unroll
        for (int ks = 0; ks < 4; ++ks) ef[ks] = *(const bf16x8*)(ep + ks * 32);
        f32x4 Fa[4] = {z4, z4, z4, z4};
#pragma unroll
        for (int ks = 0; ks < 4; ++ks)
#pragma unroll
            for (int nb = 0; nb < 4; ++nb)
                Fa[nb] = __builtin_amdgcn_mfma_f32_16x16x32_bf16(ef[ks], bfr[ks][nb], Fa[nb], 0, 0, 0);
#pragma unroll
        for (int r = 0; r < 4; ++r) {
            float s = Fa[0][r] * Qa[0][r] + Fa[1][r] * Qa[1][r] + Fa[2][r] * Qa[2][r] + Fa[3][r] * Qa[3][r];
            s += __shfl_xor(s, 1, 64);
            s += __shfl_xor(s, 2, 64);
            s += __shfl_xor(s, 4, 64);
            s += __shfl_xor(s, 8, 64);
            lossAcc += log_sigmoid(j == 0 ? s : -s);
        }
    }

    float* __restrict__ outq = out + 1;
    float* __restrict__ outp = out + 1 + (size_t)B_TOTAL * K;
#pragma unroll
    for (int r = 0; r < 4; ++r) {
        const size_t obase = (size_t)(b0 + g * 4 + r) * K + i15;
        {
            float m = fmaxf(fmaxf(Qa[0][r], Qa[1][r]), fmaxf(Qa[2][r], Qa[3][r]));
            m = fmaxf(m, __shfl_xor(m, 1, 64)); m = fmaxf(m, __shfl_xor(m, 2, 64));
            m = fmaxf(m, __shfl_xor(m, 4, 64)); m = fmaxf(m, __shfl_xor(m, 8, 64));
            float e0 = __expf(Qa[0][r] - m), e1 = __expf(Qa[1][r] - m);
            float e2 = __expf(Qa[2][r] - m), e3 = __expf(Qa[3][r] - m);
            float s = e0 + e1 + e2 + e3;
            s += __shfl_xor(s, 1, 64); s += __shfl_xor(s, 2, 64);
            s += __shfl_xor(s, 4, 64); s += __shfl_xor(s, 8, 64);
            float inv = 1.f / s;
            __builtin_nontemporal_store(e0 * inv, &outq[obase]);
            __builtin_nontemporal_store(e1 * inv, &outq[obase + 16]);
            __builtin_nontemporal_store(e2 * inv, &outq[obase + 32]);
            __builtin_nontemporal_store(e3 * inv, &outq[obase + 48]);
        }
        {
            float m = fmaxf(fmaxf(Pa[0][r], Pa[1][r]), fmaxf(Pa[2][r], Pa[3][r]));
            m = fmaxf(m, __shfl_xor(m, 1, 64)); m = fmaxf(m, __shfl_xor(m, 2, 64));
            m = fmaxf(m, __shfl_xor(m, 4, 64)); m = fmaxf(m, __shfl_xor(m, 8, 64));
            float e0 = __expf(Pa[0][r] - m), e1 = __expf(Pa[1][r] - m);
            float e2 = __expf(Pa[2][r] - m), e3 = __expf(Pa[3][r] - m);
            float s = e0 + e1 + e2 + e3;
            s += __shfl_xor(s, 1, 64); s += __shfl_xor(s, 2, 64);
            s += __shfl_xor(s, 4, 64); s += __shfl_xor(s, 8, 64);
            float inv = 1.f / s;
            __builtin_nontemporal_store(e0 * inv, &outp[obase]);
            __builtin_nontemporal_store(e1 * inv, &outp[obase + 16]);
            __builtin_nontemporal_store(e2 * inv, &outp[obase + 32]);
            __builtin_nontemporal_store(e3 * inv, &outp[obase + 48]);
        }
    }

    float tot = lossAcc;
#pragma unroll
    for (int msk = 1; msk < 64; msk <<= 1) tot += __shfl_xor(tot, msk, 64);
    if (lane == 0) atomicAdd(out, -tot / (16.f * (float)B_TOTAL));
}

// ---------------- fp32 fallback (R2 kernel, proven) ----------------
__global__ __launch_bounds__(BLOCK) void gcn_mfma_kernel(
    const int* __restrict__ w, const int* __restrict__ c, const int* __restrict__ neg,
    const float* __restrict__ node_emb, const float* __restrict__ ctx_emb,
    const float* __restrict__ comm_w, float* __restrict__ out)
{
    __shared__ __align__(16) short cw_lds[K * CWS];
    const int tid = threadIdx.x;
    const int lane = tid & 63;
    const int wid = tid >> 6;
    const int i15 = lane & 15;
    const int g = lane >> 4;

    for (int i = tid * 4; i < K * D; i += BLOCK * 4) {
        float4 v = *(const float4*)(comm_w + i);
        int row = i >> 7, col = i & 127;
        unsigned* dst = (unsigned*)&cw_lds[row * CWS + col];
        dst[0] = pkbf(v.x, v.y);
        dst[1] = pkbf(v.z, v.w);
    }
    __syncthreads();

    bf16x8 bfr[4][4];
#pragma unroll
    for (int ks = 0; ks < 4; ++ks)
#pragma unroll
        for (int nb = 0; nb < 4; ++nb)
            bfr[ks][nb] = *(const bf16x8*)&cw_lds[(nb * 16 + i15) * CWS + ks * 32 + g * 8];

    const int tile = blockIdx.x * WPB + wid;
    const int b0 = tile * TILE;
    const int bm = b0 + i15;
    const int iw = w[bm], ic = c[bm];
    int ing[NNEG];
#pragma unroll
    for (int j = 0; j < NNEG; ++j) ing[j] = neg[bm * NNEG + j];

    const f32x4 z4 = {0.f, 0.f, 0.f, 0.f};
    f32x4 Qa[4] = {z4, z4, z4, z4};
    f32x4 Pa[4] = {z4, z4, z4, z4};

#pragma unroll
    for (int ks = 0; ks < 4; ++ks) {
        const float* wp = node_emb + (size_t)iw * D + ks * 32 + g * 8;
        const float* cp = node_emb + (size_t)ic * D + ks * 32 + g * 8;
        float4 w0 = *(const float4*)wp, w1 = *(const float4*)(wp + 4);
        float4 c0 = *(const float4*)cp, c1 = *(const float4*)(cp + 4);
        FragU wf, pf;
        wf.u[0] = pkbf(w0.x, w0.y);               wf.u[1] = pkbf(w0.z, w0.w);
        wf.u[2] = pkbf(w1.x, w1.y);               wf.u[3] = pkbf(w1.z, w1.w);
        pf.u[0] = pkbf(w0.x * c0.x, w0.y * c0.y); pf.u[1] = pkbf(w0.z * c0.z, w0.w * c0.w);
        pf.u[2] = pkbf(w1.x * c1.x, w1.y * c1.y); pf.u[3] = pkbf(w1.z * c1.z, w1.w * c1.w);
#pragma unroll
        for (int nb = 0; nb < 4; ++nb) {
            Pa[nb] = __builtin_amdgcn_mfma_f32_16x16x32_bf16(wf.v, bfr[ks][nb], Pa[nb], 0, 0, 0);
            Qa[nb] = __builtin_amdgcn_mfma_f32_16x16x32_bf16(pf.v, bfr[ks][nb], Qa[nb], 0, 0, 0);
        }
    }

    float lossAcc = 0.f;
#pragma unroll
    for (int j = 0; j < 1 + NNEG; ++j) {
        const int idx = (j == 0) ? ic : ing[j - 1];
        const float* ebase = ctx_emb + (size_t)idx * D;
        f32x4 Fa[4] = {z4, z4, z4, z4};
#pragma unroll
        for (int ks = 0; ks < 4; ++ks) {
            const float* ep = ebase + ks * 32 + g * 8;
            float4 e0 = *(const float4*)ep, e1 = *(const float4*)(ep + 4);
            FragU ef;
            ef.u[0] = pkbf(e0.x, e0.y); ef.u[1] = pkbf(e0.z, e0.w);
            ef.u[2] = pkbf(e1.x, e1.y); ef.u[3] = pkbf(e1.z, e1.w);
#pragma unroll
            for (int nb = 0; nb < 4; ++nb)
                Fa[nb] = __builtin_amdgcn_mfma_f32_16x16x32_bf16(ef.v, bfr[ks][nb], Fa[nb], 0, 0, 0);
        }
#pragma unroll
        for (int r = 0; r < 4; ++r) {
            float s = Fa[0][r] * Qa[0][r] + Fa[1][r] * Qa[1][r] + Fa[2][r] * Qa[2][r] + Fa[3][r] * Qa[3][r];
            s += __shfl_xor(s, 1, 64);
            s += __shfl_xor(s, 2, 64);
            s += __shfl_xor(s, 4, 64);
            s += __shfl_xor(s, 8, 64);
            lossAcc += log_sigmoid(j == 0 ? s : -s);
        }
    }

    float* __restrict__ outq = out + 1;
    float* __restrict__ outp = out + 1 + (size_t)B_TOTAL * K;
#pragma unroll
    for (int r = 0; r < 4; ++r) {
        const size_t obase = (size_t)(b0 + g * 4 + r) * K + i15;
        {
            float m = fmaxf(fmaxf(Qa[0][r], Qa[1][r]), fmaxf(Qa[2][r], Qa[3][r]));
            m = fmaxf(m, __shfl_xor(m, 1, 64)); m = fmaxf(m, __shfl_xor(m, 2, 64));
            m = fmaxf(m, __shfl_xor(m, 4, 64)); m = fmaxf(m, __shfl_xor(m, 8, 64));
            float e0 = __expf(Qa[0][r] - m), e1 = __expf(Qa[1][r] - m);
            float e2 = __expf(Qa[2][r] - m), e3 = __expf(Qa[3][r] - m);
            float s = e0 + e1 + e2 + e3;
            s += __shfl_xor(s, 1, 64); s += __shfl_xor(s, 2, 64);
            s += __shfl_xor(s, 4, 64); s += __shfl_xor(s, 8, 64);
            float inv = 1.f / s;
            outq[obase]      = e0 * inv; outq[obase + 16] = e1 * inv;
            outq[obase + 32] = e2 * inv; outq[obase + 48] = e3 * inv;
        }
        {
            float m = fmaxf(fmaxf(Pa[0][r], Pa[1][r]), fmaxf(Pa[2][r], Pa[3][r]));
            m = fmaxf(m, __shfl_xor(m, 1, 64)); m = fmaxf(m, __shfl_xor(m, 2, 64));
            m = fmaxf(m, __shfl_xor(m, 4, 64)); m = fmaxf(m, __shfl_xor(m, 8, 64));
            float e0 = __expf(Pa[0][r] - m), e1 = __expf(Pa[1][r] - m);
            float e2 = __expf(Pa[2][r] - m), e3 = __expf(Pa[3][r] - m);
            float s = e0 + e1 + e2 + e3;
            s += __shfl_xor(s, 1, 64); s += __shfl_xor(s, 2, 64);
            s += __shfl_xor(s, 4, 64); s += __shfl_xor(s, 8, 64);
            float inv = 1.f / s;
            outp[obase]      = e0 * inv; outp[obase + 16] = e1 * inv;
            outp[obase + 32] = e2 * inv; outp[obase + 48] = e3 * inv;
        }
    }

    float tot = lossAcc;
#pragma unroll
    for (int msk = 1; msk < 64; msk <<= 1) tot += __shfl_xor(tot, msk, 64);
    if (lane == 0) atomicAdd(out, -tot / (16.f * (float)B_TOTAL));
}

extern "C" void kernel_launch(void* const* d_in, const int* in_sizes, int n_in,
                              void* d_out, int out_size, void* d_ws, size_t ws_size,
                              hipStream_t stream) {
    const int* w = (const int*)d_in[0];
    const int* c = (const int*)d_in[1];
    const int* neg = (const int*)d_in[2];
    // d_in[3] = temp (unused)
    const float* node_emb = (const float*)d_in[4];
    const float* ctx_emb = (const float*)d_in[5];
    const float* comm_w = (const float*)d_in[6];
    float* out = (float*)d_out;

    const size_t tbl_elems = (size_t)SIZE_N * D;
    const size_t need = 2 * tbl_elems * sizeof(short);   // 51.2 MB

    if (ws_size >= need) {
        short* nodeb = (short*)d_ws;
        short* ctxb = nodeb + tbl_elems;
        const int cblocks = (int)((tbl_elems / 8 + BLOCK - 1) / BLOCK);   // 6250
        convert_tables<<<cblocks, BLOCK, 0, stream>>>(node_emb, ctx_emb, nodeb, ctxb, out);
        gcn_mfma_bf16<<<GRID, BLOCK, 0, stream>>>(w, c, neg, nodeb, ctxb, comm_w, out);
    } else {
        zero_loss<<<1, 64, 0, stream>>>(out);
        gcn_mfma_kernel<<<GRID, BLOCK, 0, stream>>>(w, c, neg, node_emb, ctx_emb, comm_w, out);
    }
}

// Round 4
// 283.224 us; speedup vs baseline: 1.8278x; 1.0265x over previous
//
#include <hip/hip_runtime.h>
#include <math.h>

#define SIZE_N 100000
#define B_TOTAL 131072
#define D 128
#define K 64
#define NNEG 5
#define TILE 16
#define BLOCK 256
#define WPB 4
#define NTILES (B_TOTAL / TILE)        // 8192
#define GRID (NTILES / WPB)            // 2048
#define CWS 136                        // fallback LDS stride

typedef short bf16x8 __attribute__((ext_vector_type(8)));
typedef float f32x4 __attribute__((ext_vector_type(4)));

union FragU { unsigned u[4]; bf16x8 v; };

// round-to-nearest-even fp32 -> bf16 (upper 16 bits)
__device__ __forceinline__ unsigned rne_hi(float x) {
    unsigned u = __float_as_uint(x);
    return (u + 0x7fffu + ((u >> 16) & 1u)) & 0xffff0000u;
}
__device__ __forceinline__ unsigned pkbf(float lo, float hi) {
    return (rne_hi(lo) >> 16) | rne_hi(hi);
}

__device__ __forceinline__ float log_sigmoid(float x) {
    return fminf(x, 0.f) - __logf(1.f + __expf(-fabsf(x)));
}

__global__ void zero_loss(float* out) { if (threadIdx.x == 0) out[0] = 0.f; }

// fp32 -> bf16 for both tables + comm_w; fused loss-zero
__global__ __launch_bounds__(BLOCK) void convert_tables(
    const float* __restrict__ a, const float* __restrict__ b, const float* __restrict__ cw,
    short* __restrict__ oa, short* __restrict__ ob, short* __restrict__ ocw,
    float* __restrict__ out)
{
    const size_t i = ((size_t)blockIdx.x * BLOCK + threadIdx.x) * 8;
    const size_t n = (size_t)SIZE_N * D;           // 12.8M, = 6250*2048 exactly
    if (i < n) {
        {
            float4 v0 = *(const float4*)(a + i), v1 = *(const float4*)(a + i + 4);
            FragU f;
            f.u[0] = pkbf(v0.x, v0.y); f.u[1] = pkbf(v0.z, v0.w);
            f.u[2] = pkbf(v1.x, v1.y); f.u[3] = pkbf(v1.z, v1.w);
            *(bf16x8*)(oa + i) = f.v;
        }
        {
            float4 v0 = *(const float4*)(b + i), v1 = *(const float4*)(b + i + 4);
            FragU f;
            f.u[0] = pkbf(v0.x, v0.y); f.u[1] = pkbf(v0.z, v0.w);
            f.u[2] = pkbf(v1.x, v1.y); f.u[3] = pkbf(v1.z, v1.w);
            *(bf16x8*)(ob + i) = f.v;
        }
    }
    if (blockIdx.x == 0) {
        if (threadIdx.x == 0) out[0] = 0.f;
#pragma unroll
        for (int t = 0; t < 4; ++t) {
            const int j = (threadIdx.x * 4 + t) * 8;   // 0..8184, covers K*D=8192
            float4 v0 = *(const float4*)(cw + j), v1 = *(const float4*)(cw + j + 4);
            FragU f;
            f.u[0] = pkbf(v0.x, v0.y); f.u[1] = pkbf(v0.z, v0.w);
            f.u[2] = pkbf(v1.x, v1.y); f.u[3] = pkbf(v1.z, v1.w);
            *(bf16x8*)(ocw + j) = f.v;
        }
    }
}

// ---------------- barrier-free bf16 main kernel ----------------
__global__ __launch_bounds__(BLOCK, 3) void gcn_mfma_bf16(
    const int* __restrict__ w, const int* __restrict__ c, const int* __restrict__ neg,
    const short* __restrict__ nodeb, const short* __restrict__ ctxb,
    const short* __restrict__ cwb, float* __restrict__ out)
{
    const int tid = threadIdx.x;
    const int lane = tid & 63;
    const int wid = tid >> 6;
    const int i15 = lane & 15;
    const int g = lane >> 4;

    const int tile = blockIdx.x * WPB + wid;
    const int b0 = tile * TILE;
    const int bm = b0 + i15;

    // (1) index loads — first in issue order, nothing blocks them
    const int iw = w[bm];
    const int ic = c[bm];
    int ing[NNEG];
#pragma unroll
    for (int j = 0; j < NNEG; ++j) ing[j] = neg[bm * NNEG + j];

    // (2) comm_w fragments straight from global (16 KB -> L1-resident); address-ready,
    //     these issue while the idx loads are in flight
    bf16x8 bfr[4][4];
#pragma unroll
    for (int ks = 0; ks < 4; ++ks)
#pragma unroll
        for (int nb = 0; nb < 4; ++nb)
            bfr[ks][nb] = *(const bf16x8*)&cwb[(nb * 16 + i15) * D + ks * 32 + g * 8];

    // (3) row gathers — issue as soon as idx values land
    const short* wp = nodeb + (size_t)iw * D + g * 8;
    const short* cp = nodeb + (size_t)ic * D + g * 8;
    FragU wf[4], cf[4];
#pragma unroll
    for (int ks = 0; ks < 4; ++ks) {
        wf[ks].v = *(const bf16x8*)(wp + ks * 32);
        cf[ks].v = *(const bf16x8*)(cp + ks * 32);
    }
    const short* e0p = ctxb + (size_t)ic * D + g * 8;
    bf16x8 ef[4];
#pragma unroll
    for (int ks = 0; ks < 4; ++ks) ef[ks] = *(const bf16x8*)(e0p + ks * 32);

    // (4) Q/P GEMMs
    const f32x4 z4 = {0.f, 0.f, 0.f, 0.f};
    f32x4 Qa[4] = {z4, z4, z4, z4};
    f32x4 Pa[4] = {z4, z4, z4, z4};
#pragma unroll
    for (int ks = 0; ks < 4; ++ks) {
        FragU pf;
#pragma unroll
        for (int t = 0; t < 4; ++t) {
            float al = __uint_as_float(wf[ks].u[t] << 16);
            float ah = __uint_as_float(wf[ks].u[t] & 0xffff0000u);
            float bl = __uint_as_float(cf[ks].u[t] << 16);
            float bh = __uint_as_float(cf[ks].u[t] & 0xffff0000u);
            pf.u[t] = pkbf(al * bl, ah * bh);
        }
#pragma unroll
        for (int nb = 0; nb < 4; ++nb) {
            Pa[nb] = __builtin_amdgcn_mfma_f32_16x16x32_bf16(wf[ks].v, bfr[ks][nb], Pa[nb], 0, 0, 0);
            Qa[nb] = __builtin_amdgcn_mfma_f32_16x16x32_bf16(pf.v, bfr[ks][nb], Qa[nb], 0, 0, 0);
        }
    }

    // (5) pos/neg loop with 1-ahead ctx prefetch
    float lossAcc = 0.f;
#pragma unroll
    for (int j = 0; j < 1 + NNEG; ++j) {
        bf16x8 efn[4];
        if (j < NNEG) {
            const short* ep = ctxb + (size_t)ing[j] * D + g * 8;
#pragma unroll
            for (int ks = 0; ks < 4; ++ks) efn[ks] = *(const bf16x8*)(ep + ks * 32);
        }
        f32x4 Fa[4] = {z4, z4, z4, z4};
#pragma unroll
        for (int ks = 0; ks < 4; ++ks)
#pragma unroll
            for (int nb = 0; nb < 4; ++nb)
                Fa[nb] = __builtin_amdgcn_mfma_f32_16x16x32_bf16(ef[ks], bfr[ks][nb], Fa[nb], 0, 0, 0);
#pragma unroll
        for (int r = 0; r < 4; ++r) {
            float s = Fa[0][r] * Qa[0][r] + Fa[1][r] * Qa[1][r] + Fa[2][r] * Qa[2][r] + Fa[3][r] * Qa[3][r];
            s += __shfl_xor(s, 1, 64);
            s += __shfl_xor(s, 2, 64);
            s += __shfl_xor(s, 4, 64);
            s += __shfl_xor(s, 8, 64);
            lossAcc += log_sigmoid(j == 0 ? s : -s);
        }
#pragma unroll
        for (int ks = 0; ks < 4; ++ks) ef[ks] = efn[ks];
    }

    // (6) epilogue: softmax(q), prior; nontemporal stores
    float* __restrict__ outq = out + 1;
    float* __restrict__ outp = out + 1 + (size_t)B_TOTAL * K;
#pragma unroll
    for (int r = 0; r < 4; ++r) {
        const size_t obase = (size_t)(b0 + g * 4 + r) * K + i15;
        {
            float m = fmaxf(fmaxf(Qa[0][r], Qa[1][r]), fmaxf(Qa[2][r], Qa[3][r]));
            m = fmaxf(m, __shfl_xor(m, 1, 64)); m = fmaxf(m, __shfl_xor(m, 2, 64));
            m = fmaxf(m, __shfl_xor(m, 4, 64)); m = fmaxf(m, __shfl_xor(m, 8, 64));
            float e0 = __expf(Qa[0][r] - m), e1 = __expf(Qa[1][r] - m);
            float e2 = __expf(Qa[2][r] - m), e3 = __expf(Qa[3][r] - m);
            float s = e0 + e1 + e2 + e3;
            s += __shfl_xor(s, 1, 64); s += __shfl_xor(s, 2, 64);
            s += __shfl_xor(s, 4, 64); s += __shfl_xor(s, 8, 64);
            float inv = 1.f / s;
            __builtin_nontemporal_store(e0 * inv, &outq[obase]);
            __builtin_nontemporal_store(e1 * inv, &outq[obase + 16]);
            __builtin_nontemporal_store(e2 * inv, &outq[obase + 32]);
            __builtin_nontemporal_store(e3 * inv, &outq[obase + 48]);
        }
        {
            float m = fmaxf(fmaxf(Pa[0][r], Pa[1][r]), fmaxf(Pa[2][r], Pa[3][r]));
            m = fmaxf(m, __shfl_xor(m, 1, 64)); m = fmaxf(m, __shfl_xor(m, 2, 64));
            m = fmaxf(m, __shfl_xor(m, 4, 64)); m = fmaxf(m, __shfl_xor(m, 8, 64));
            float e0 = __expf(Pa[0][r] - m), e1 = __expf(Pa[1][r] - m);
            float e2 = __expf(Pa[2][r] - m), e3 = __expf(Pa[3][r] - m);
            float s = e0 + e1 + e2 + e3;
            s += __shfl_xor(s, 1, 64); s += __shfl_xor(s, 2, 64);
            s += __shfl_xor(s, 4, 64); s += __shfl_xor(s, 8, 64);
            float inv = 1.f / s;
            __builtin_nontemporal_store(e0 * inv, &outp[obase]);
            __builtin_nontemporal_store(e1 * inv, &outp[obase + 16]);
            __builtin_nontemporal_store(e2 * inv, &outp[obase + 32]);
            __builtin_nontemporal_store(e3 * inv, &outp[obase + 48]);
        }
    }

    float tot = lossAcc;
#pragma unroll
    for (int msk = 1; msk < 64; msk <<= 1) tot += __shfl_xor(tot, msk, 64);
    if (lane == 0) atomicAdd(out, -tot / (16.f * (float)B_TOTAL));
}

// ---------------- fp32 fallback (R2 kernel, proven) ----------------
__global__ __launch_bounds__(BLOCK) void gcn_mfma_kernel(
    const int* __restrict__ w, const int* __restrict__ c, const int* __restrict__ neg,
    const float* __restrict__ node_emb, const float* __restrict__ ctx_emb,
    const float* __restrict__ comm_w, float* __restrict__ out)
{
    __shared__ __align__(16) short cw_lds[K * CWS];
    const int tid = threadIdx.x;
    const int lane = tid & 63;
    const int wid = tid >> 6;
    const int i15 = lane & 15;
    const int g = lane >> 4;

    for (int i = tid * 4; i < K * D; i += BLOCK * 4) {
        float4 v = *(const float4*)(comm_w + i);
        int row = i >> 7, col = i & 127;
        unsigned* dst = (unsigned*)&cw_lds[row * CWS + col];
        dst[0] = pkbf(v.x, v.y);
        dst[1] = pkbf(v.z, v.w);
    }
    __syncthreads();

    bf16x8 bfr[4][4];
#pragma unroll
    for (int ks = 0; ks < 4; ++ks)
#pragma unroll
        for (int nb = 0; nb < 4; ++nb)
            bfr[ks][nb] = *(const bf16x8*)&cw_lds[(nb * 16 + i15) * CWS + ks * 32 + g * 8];

    const int tile = blockIdx.x * WPB + wid;
    const int b0 = tile * TILE;
    const int bm = b0 + i15;
    const int iw = w[bm], ic = c[bm];
    int ing[NNEG];
#pragma unroll
    for (int j = 0; j < NNEG; ++j) ing[j] = neg[bm * NNEG + j];

    const f32x4 z4 = {0.f, 0.f, 0.f, 0.f};
    f32x4 Qa[4] = {z4, z4, z4, z4};
    f32x4 Pa[4] = {z4, z4, z4, z4};

#pragma unroll
    for (int ks = 0; ks < 4; ++ks) {
        const float* wp = node_emb + (size_t)iw * D + ks * 32 + g * 8;
        const float* cp = node_emb + (size_t)ic * D + ks * 32 + g * 8;
        float4 w0 = *(const float4*)wp, w1 = *(const float4*)(wp + 4);
        float4 c0 = *(const float4*)cp, c1 = *(const float4*)(cp + 4);
        FragU wf, pf;
        wf.u[0] = pkbf(w0.x, w0.y);               wf.u[1] = pkbf(w0.z, w0.w);
        wf.u[2] = pkbf(w1.x, w1.y);               wf.u[3] = pkbf(w1.z, w1.w);
        pf.u[0] = pkbf(w0.x * c0.x, w0.y * c0.y); pf.u[1] = pkbf(w0.z * c0.z, w0.w * c0.w);
        pf.u[2] = pkbf(w1.x * c1.x, w1.y * c1.y); pf.u[3] = pkbf(w1.z * c1.z, w1.w * c1.w);
#pragma unroll
        for (int nb = 0; nb < 4; ++nb) {
            Pa[nb] = __builtin_amdgcn_mfma_f32_16x16x32_bf16(wf.v, bfr[ks][nb], Pa[nb], 0, 0, 0);
            Qa[nb] = __builtin_amdgcn_mfma_f32_16x16x32_bf16(pf.v, bfr[ks][nb], Qa[nb], 0, 0, 0);
        }
    }

    float lossAcc = 0.f;
#pragma unroll
    for (int j = 0; j < 1 + NNEG; ++j) {
        const int idx = (j == 0) ? ic : ing[j - 1];
        const float* ebase = ctx_emb + (size_t)idx * D;
        f32x4 Fa[4] = {z4, z4, z4, z4};
#pragma unroll
        for (int ks = 0; ks < 4; ++ks) {
            const float* ep = ebase + ks * 32 + g * 8;
            float4 e0 = *(const float4*)ep, e1 = *(const float4*)(ep + 4);
            FragU ef;
            ef.u[0] = pkbf(e0.x, e0.y); ef.u[1] = pkbf(e0.z, e0.w);
            ef.u[2] = pkbf(e1.x, e1.y); ef.u[3] = pkbf(e1.z, e1.w);
#pragma unroll
            for (int nb = 0; nb < 4; ++nb)
                Fa[nb] = __builtin_amdgcn_mfma_f32_16x16x32_bf16(ef.v, bfr[ks][nb], Fa[nb], 0, 0, 0);
        }
#pragma unroll
        for (int r = 0; r < 4; ++r) {
            float s = Fa[0][r] * Qa[0][r] + Fa[1][r] * Qa[1][r] + Fa[2][r] * Qa[2][r] + Fa[3][r] * Qa[3][r];
            s += __shfl_xor(s, 1, 64);
            s += __shfl_xor(s, 2, 64);
            s += __shfl_xor(s, 4, 64);
            s += __shfl_xor(s, 8, 64);
            lossAcc += log_sigmoid(j == 0 ? s : -s);
        }
    }

    float* __restrict__ outq = out + 1;
    float* __restrict__ outp = out + 1 + (size_t)B_TOTAL * K;
#pragma unroll
    for (int r = 0; r < 4; ++r) {
        const size_t obase = (size_t)(b0 + g * 4 + r) * K + i15;
        {
            float m = fmaxf(fmaxf(Qa[0][r], Qa[1][r]), fmaxf(Qa[2][r], Qa[3][r]));
            m = fmaxf(m, __shfl_xor(m, 1, 64)); m = fmaxf(m, __shfl_xor(m, 2, 64));
            m = fmaxf(m, __shfl_xor(m, 4, 64)); m = fmaxf(m, __shfl_xor(m, 8, 64));
            float e0 = __expf(Qa[0][r] - m), e1 = __expf(Qa[1][r] - m);
            float e2 = __expf(Qa[2][r] - m), e3 = __expf(Qa[3][r] - m);
            float s = e0 + e1 + e2 + e3;
            s += __shfl_xor(s, 1, 64); s += __shfl_xor(s, 2, 64);
            s += __shfl_xor(s, 4, 64); s += __shfl_xor(s, 8, 64);
            float inv = 1.f / s;
            outq[obase]      = e0 * inv; outq[obase + 16] = e1 * inv;
            outq[obase + 32] = e2 * inv; outq[obase + 48] = e3 * inv;
        }
        {
            float m = fmaxf(fmaxf(Pa[0][r], Pa[1][r]), fmaxf(Pa[2][r], Pa[3][r]));
            m = fmaxf(m, __shfl_xor(m, 1, 64)); m = fmaxf(m, __shfl_xor(m, 2, 64));
            m = fmaxf(m, __shfl_xor(m, 4, 64)); m = fmaxf(m, __shfl_xor(m, 8, 64));
            float e0 = __expf(Pa[0][r] - m), e1 = __expf(Pa[1][r] - m);
            float e2 = __expf(Pa[2][r] - m), e3 = __expf(Pa[3][r] - m);
            float s = e0 + e1 + e2 + e3;
            s += __shfl_xor(s, 1, 64); s += __shfl_xor(s, 2, 64);
            s += __shfl_xor(s, 4, 64); s += __shfl_xor(s, 8, 64);
            float inv = 1.f / s;
            outp[obase]      = e0 * inv; outp[obase + 16] = e1 * inv;
            outp[obase + 32] = e2 * inv; outp[obase + 48] = e3 * inv;
        }
    }

    float tot = lossAcc;
#pragma unroll
    for (int msk = 1; msk < 64; msk <<= 1) tot += __shfl_xor(tot, msk, 64);
    if (lane == 0) atomicAdd(out, -tot / (16.f * (float)B_TOTAL));
}

extern "C" void kernel_launch(void* const* d_in, const int* in_sizes, int n_in,
                              void* d_out, int out_size, void* d_ws, size_t ws_size,
                              hipStream_t stream) {
    const int* w = (const int*)d_in[0];
    const int* c = (const int*)d_in[1];
    const int* neg = (const int*)d_in[2];
    // d_in[3] = temp (unused)
    const float* node_emb = (const float*)d_in[4];
    const float* ctx_emb = (const float*)d_in[5];
    const float* comm_w = (const float*)d_in[6];
    float* out = (float*)d_out;

    const size_t tbl_elems = (size_t)SIZE_N * D;
    const size_t need = (2 * tbl_elems + (size_t)K * D) * sizeof(short);   // 51.2 MB + 16 KB

    if (ws_size >= need) {
        short* nodeb = (short*)d_ws;
        short* ctxb = nodeb + tbl_elems;
        short* cwb = ctxb + tbl_elems;
        const int cblocks = (int)((tbl_elems / 8 + BLOCK - 1) / BLOCK);   // 6250
        convert_tables<<<cblocks, BLOCK, 0, stream>>>(node_emb, ctx_emb, comm_w,
                                                      nodeb, ctxb, cwb, out);
        gcn_mfma_bf16<<<GRID, BLOCK, 0, stream>>>(w, c, neg, nodeb, ctxb, cwb, out);
    } else {
        zero_loss<<<1, 64, 0, stream>>>(out);
        gcn_mfma_kernel<<<GRID, BLOCK, 0, stream>>>(w, c, neg, node_emb, ctx_emb, comm_w, out);
    }
}